// Round 7
// baseline (783.656 us; speedup 1.0000x reference)
//
#include <hip/hip_runtime.h>
#include <hip/hip_bf16.h>

typedef __hip_bfloat16 bf16;
typedef __attribute__((ext_vector_type(8))) short short8;
typedef __attribute__((ext_vector_type(4))) float floatx4;

#define B_ 4
#define S_ 1024
#define DIM_ 2048
#define H_ 32
#define HD_ 64
#define R_ 16
#define BS_ (B_*S_)   // 4096

typedef __attribute__((address_space(1))) void GVoid;
typedef __attribute__((address_space(3))) void LVoid;
#define GLDS16(gp, lp) __builtin_amdgcn_global_load_lds((GVoid*)(gp), (LVoid*)(lp), 16, 0, 0)

__device__ __forceinline__ float b2f(bf16 v){ return __bfloat162float(v); }
__device__ __forceinline__ float elu1f(float x){ return x > 0.f ? x + 1.f : __expf(x); }
__device__ __forceinline__ float sigmoidf(float x){ return 1.f/(1.f + __expf(-x)); }
__device__ __forceinline__ float loadf(bf16 v){ return __bfloat162float(v); }
__device__ __forceinline__ float loadf(float v){ return v; }

// dtype-adaptive input read: f=1 -> bf16, f=0 -> fp32 (uniform branch).
__device__ __forceinline__ float dread(const void* p, size_t i, int f){
    float r;
    if (f) r = __bfloat162float(((const bf16*)p)[i]);
    else   r = ((const float*)p)[i];
    return r;
}
__device__ __forceinline__ void dwrite(void* p, size_t i, float v, int f){
    if (f) ((bf16*)p)[i] = __float2bfloat16(v);
    else   ((float*)p)[i] = v;
}

// ---------------------------------------------------------------------------
// dtype detect (same every call; graph-safe)
// ---------------------------------------------------------------------------
__global__ void detect_kernel(const void* __restrict__ x, int* __restrict__ flag){
    __shared__ int cnt[256];
    int t = threadIdx.x;
    int c = 0;
    for (int i = t; i < 4096; i += 256){
        float v = __bfloat162float(((const bf16*)x)[i]);
        float a = fabsf(v);
        if (a > 1e-3f && a < 1e3f) c++;
    }
    cnt[t] = c;
    __syncthreads();
    if (t == 0){
        int s = 0;
        for (int i = 0; i < 256; ++i) s += cnt[i];
        *flag = (s > 3686) ? 1 : 0;
    }
}

// ---------------------------------------------------------------------------
// convert input (fp32 or bf16 per flag) -> bf16 workspace copy, x8 vectorized
// ---------------------------------------------------------------------------
__global__ void convert_kernel(const void* __restrict__ src, bf16* __restrict__ dst,
                               int n, const int* __restrict__ flagp){
    int i = (blockIdx.x * 256 + threadIdx.x) * 8;
    if (i >= n) return;
    short8 o;
    if (*flagp){
        o = *(const short8*)((const bf16*)src + i);
    } else {
        const float* s = (const float*)src + i;
        float4 v0 = *(const float4*)(s);
        float4 v1 = *(const float4*)(s + 4);
        ((bf16*)&o)[0] = __float2bfloat16(v0.x);
        ((bf16*)&o)[1] = __float2bfloat16(v0.y);
        ((bf16*)&o)[2] = __float2bfloat16(v0.z);
        ((bf16*)&o)[3] = __float2bfloat16(v0.w);
        ((bf16*)&o)[4] = __float2bfloat16(v1.x);
        ((bf16*)&o)[5] = __float2bfloat16(v1.y);
        ((bf16*)&o)[6] = __float2bfloat16(v1.z);
        ((bf16*)&o)[7] = __float2bfloat16(v1.w);
    }
    *(short8*)(dst + i) = o;
}

// ---------------------------------------------------------------------------
// fused weight prep: W'[n,k] = W[n,k] + sum_r L2[n,r] * L1[r,k]   -> bf16
// ---------------------------------------------------------------------------
template<typename T>
__device__ __forceinline__ void wprep_body(const T* __restrict__ W,
                                           const T* __restrict__ L1,
                                           const T* __restrict__ L2,
                                           bf16* __restrict__ dst){
    int n = blockIdx.y;
    int k = blockIdx.x * 256 + threadIdx.x;
    size_t nk = (size_t)n * DIM_ + k;
    float acc = loadf(W[nk]);
    #pragma unroll
    for (int r = 0; r < 16; ++r)
        acc += loadf(L2[n*16 + r]) * loadf(L1[(size_t)r*DIM_ + k]);
    dst[nk] = __float2bfloat16(acc);
}
__global__ __launch_bounds__(256)
void wprep_kernel(const void* __restrict__ W, const void* __restrict__ L1,
                  const void* __restrict__ L2, const int* __restrict__ flagp,
                  bf16* __restrict__ dst){
    if (*flagp) wprep_body((const bf16*)W, (const bf16*)L1, (const bf16*)L2, dst);
    else        wprep_body((const float*)W, (const float*)L1, (const float*)L2, dst);
}

// one launch for all 3 QKV weights: blockIdx.z selects the triplet
__global__ __launch_bounds__(256)
void wprep3_kernel(const void* __restrict__ W0, const void* __restrict__ W1,
                   const void* __restrict__ W2,
                   const void* __restrict__ L1q, const void* __restrict__ L1k,
                   const void* __restrict__ L1v,
                   const void* __restrict__ L2q, const void* __restrict__ L2k,
                   const void* __restrict__ L2v,
                   const int* __restrict__ flagp,
                   bf16* __restrict__ d0, bf16* __restrict__ d1,
                   bf16* __restrict__ d2){
    int z = blockIdx.z;
    const void* W  = (z==0) ? W0 : (z==1) ? W1 : W2;
    const void* L1 = (z==0) ? L1q : (z==1) ? L1k : L1v;
    const void* L2 = (z==0) ? L2q : (z==1) ? L2k : L2v;
    bf16* dst = (z==0) ? d0 : (z==1) ? d1 : d2;
    if (*flagp) wprep_body((const bf16*)W, (const bf16*)L1, (const bf16*)L2, dst);
    else        wprep_body((const float*)W, (const float*)L1, (const float*)L2, dst);
}

// ---------------------------------------------------------------------------
// MFMA GEMM: C[m,n] = sum_k A[m,k]*Bw[n,k]  (m97 structure, single-buffer —
// round-4 harness-verified version)
// ---------------------------------------------------------------------------
template<int CMODE>   // 1: bf16 ws out; 0: dual-dtype d_out
__global__ __launch_bounds__(256)
void gemm_mfma_kernel(const bf16* __restrict__ A, const bf16* __restrict__ Bw,
                      const int* __restrict__ flagp, void* __restrict__ C) {
    __shared__ bf16 Als[128*32];
    __shared__ bf16 Bls[128*32];
    int tid = threadIdx.x;
    int w = tid >> 6, lane = tid & 63;
    int wr = w >> 1, wc = w & 1;
    int rm0 = blockIdx.y * 128;
    int cn0 = blockIdx.x * 128;

    const bf16* gA = A  + (size_t)(rm0 + w*32 + (lane>>2)) * DIM_ + (lane&3)*8;
    const bf16* gB = Bw + (size_t)(cn0 + w*32 + (lane>>2)) * DIM_ + (lane&3)*8;
    bf16* lA0 = Als + (w*32)*32;
    bf16* lA1 = Als + (w*32+16)*32;
    bf16* lB0 = Bls + (w*32)*32;
    bf16* lB1 = Bls + (w*32+16)*32;

    floatx4 acc[4][4];
    #pragma unroll
    for (int i = 0; i < 4; ++i)
        #pragma unroll
        for (int j = 0; j < 4; ++j) acc[i][j] = (floatx4){0.f,0.f,0.f,0.f};

    int aoff[4], boff[4];
    #pragma unroll
    for (int i = 0; i < 4; ++i) {
        aoff[i] = (wr*64 + i*16 + (lane&15))*32 + (lane>>4)*8;
        boff[i] = (wc*64 + i*16 + (lane&15))*32 + (lane>>4)*8;
    }

    for (int kk = 0; kk < DIM_; kk += 32) {
        GLDS16(gA + kk,             lA0);
        GLDS16(gA + 16*DIM_ + kk,   lA1);
        GLDS16(gB + kk,             lB0);
        GLDS16(gB + 16*DIM_ + kk,   lB1);
        __syncthreads();
        short8 af[4], bf_[4];
        #pragma unroll
        for (int i = 0; i < 4; ++i) {
            af[i]  = *(const short8*)(Als + aoff[i]);
            bf_[i] = *(const short8*)(Bls + boff[i]);
        }
        #pragma unroll
        for (int i = 0; i < 4; ++i)
            #pragma unroll
            for (int j = 0; j < 4; ++j)
                acc[i][j] = __builtin_amdgcn_mfma_f32_16x16x32_bf16(
                    af[i], bf_[j], acc[i][j], 0, 0, 0);
        __syncthreads();
    }

    int f = (CMODE==0) ? *flagp : 1;
    #pragma unroll
    for (int i = 0; i < 4; ++i) {
        #pragma unroll
        for (int reg = 0; reg < 4; ++reg) {
            int m_loc = wr*64 + i*16 + (lane>>4)*4 + reg;
            #pragma unroll
            for (int j = 0; j < 4; ++j) {
                int n_loc = wc*64 + j*16 + (lane&15);
                float val = acc[i][j][reg];
                size_t idx = (size_t)(rm0 + m_loc) * DIM_ + cn0 + n_loc;
                if (CMODE==1) ((bf16*)C)[idx] = __float2bfloat16(val);
                else          dwrite(C, idx, val, f);
            }
        }
    }
}

// fused QKV GEMM: grid (48, 32); blockIdx.x>>4 selects weight/output pair
// (round-4 harness-verified single-buffer version)
__global__ __launch_bounds__(256)
void gemm_mfma3_kernel(const bf16* __restrict__ A,
                       const bf16* __restrict__ B0, const bf16* __restrict__ B1,
                       const bf16* __restrict__ B2,
                       bf16* __restrict__ C0, bf16* __restrict__ C1,
                       bf16* __restrict__ C2) {
    __shared__ bf16 Als[128*32];
    __shared__ bf16 Bls[128*32];
    int tid = threadIdx.x;
    int w = tid >> 6, lane = tid & 63;
    int wr = w >> 1, wc = w & 1;
    int rm0 = blockIdx.y * 128;
    int wz  = blockIdx.x >> 4;
    int cn0 = (blockIdx.x & 15) * 128;
    const bf16* Bw = (wz==0) ? B0 : (wz==1) ? B1 : B2;
    bf16* C        = (wz==0) ? C0 : (wz==1) ? C1 : C2;

    const bf16* gA = A  + (size_t)(rm0 + w*32 + (lane>>2)) * DIM_ + (lane&3)*8;
    const bf16* gB = Bw + (size_t)(cn0 + w*32 + (lane>>2)) * DIM_ + (lane&3)*8;
    bf16* lA0 = Als + (w*32)*32;
    bf16* lA1 = Als + (w*32+16)*32;
    bf16* lB0 = Bls + (w*32)*32;
    bf16* lB1 = Bls + (w*32+16)*32;

    floatx4 acc[4][4];
    #pragma unroll
    for (int i = 0; i < 4; ++i)
        #pragma unroll
        for (int j = 0; j < 4; ++j) acc[i][j] = (floatx4){0.f,0.f,0.f,0.f};

    int aoff[4], boff[4];
    #pragma unroll
    for (int i = 0; i < 4; ++i) {
        aoff[i] = (wr*64 + i*16 + (lane&15))*32 + (lane>>4)*8;
        boff[i] = (wc*64 + i*16 + (lane&15))*32 + (lane>>4)*8;
    }

    for (int kk = 0; kk < DIM_; kk += 32) {
        GLDS16(gA + kk,             lA0);
        GLDS16(gA + 16*DIM_ + kk,   lA1);
        GLDS16(gB + kk,             lB0);
        GLDS16(gB + 16*DIM_ + kk,   lB1);
        __syncthreads();
        short8 af[4], bf_[4];
        #pragma unroll
        for (int i = 0; i < 4; ++i) {
            af[i]  = *(const short8*)(Als + aoff[i]);
            bf_[i] = *(const short8*)(Bls + boff[i]);
        }
        #pragma unroll
        for (int i = 0; i < 4; ++i)
            #pragma unroll
            for (int j = 0; j < 4; ++j)
                acc[i][j] = __builtin_amdgcn_mfma_f32_16x16x32_bf16(
                    af[i], bf_[j], acc[i][j], 0, 0, 0);
        __syncthreads();
    }

    #pragma unroll
    for (int i = 0; i < 4; ++i) {
        #pragma unroll
        for (int reg = 0; reg < 4; ++reg) {
            int m_loc = wr*64 + i*16 + (lane>>4)*4 + reg;
            #pragma unroll
            for (int j = 0; j < 4; ++j) {
                int n_loc = wc*64 + j*16 + (lane&15);
                size_t idx = (size_t)(rm0 + m_loc) * DIM_ + cn0 + n_loc;
                C[idx] = __float2bfloat16(acc[i][j][reg]);
            }
        }
    }
}

// ---------------------------------------------------------------------------
// per (b,h,s-tile): PARTIAL mem_l/mem_q outer-product accumulation + nrm.
// Grid (B*H, 8); each block covers 128 s-rows; partials to pbuf*.
// qscore FUSED: wave w owns row sl=w; dot(pq, raw_k) via wave shfl-reduce.
// ---------------------------------------------------------------------------
__global__ __launch_bounds__(256)
void mem_kernel(const void* __restrict__ ck, const void* __restrict__ cv,
                const void* __restrict__ pq,
                const int* __restrict__ flagp,
                float* __restrict__ pbufL, float* __restrict__ pbufQ,
                float* __restrict__ pbufN) {
    int f = *flagp;
    __shared__ float ks[4][64], vs[4][64], fv[4][64];
    int bh = blockIdx.x;
    int st = blockIdx.y;                 // s-tile of 128 rows
    int b = bh >> 5, h = bh & 31;
    int t = threadIdx.x;
    int e = t & 63;
    int dg = t >> 6;
    float pqd = dread(pq, ((size_t)b*H_ + h)*HD_ + e, f);
    float accL[16] = {};
    float accQ[16] = {};
    float nsum = 0.f;
    int sbase = st * 128;
    for (int s0 = 0; s0 < 128; s0 += 4) {
        int sl = t >> 6, d = t & 63;
        int s = sbase + s0 + sl;
        size_t base = (((size_t)b*S_ + s)*H_ + h)*HD_ + d;
        float kraw = dread(ck, base, f);
        float kv = elu1f(kraw);
        float vv = dread(cv, base, f);
        float dot = pqd * kraw;
        for (int off = 32; off; off >>= 1) dot += __shfl_xor(dot, off, 64);
        float sg = sigmoidf(dot * 0.125f);
        ks[sl][d] = kv;
        vs[sl][d] = vv;
        fv[sl][d] = vv * sg;
        __syncthreads();
        #pragma unroll
        for (int s2 = 0; s2 < 4; ++s2) {
            float ve = vs[s2][e];
            float fe = fv[s2][e];
            #pragma unroll
            for (int dd = 0; dd < 16; ++dd) {
                float kk = ks[s2][dg*16 + dd];
                accL[dd] += kk * ve;
                accQ[dd] += kk * fe;
            }
        }
        if (t < 64) {
            #pragma unroll
            for (int s2 = 0; s2 < 4; ++s2) nsum += ks[s2][t];
        }
        __syncthreads();
    }
    size_t pb = ((size_t)bh*8 + st) * 4096;
    #pragma unroll
    for (int dd = 0; dd < 16; ++dd) {
        int d = dg*16 + dd;
        pbufL[pb + d*64 + e] = accL[dd];
        pbufQ[pb + d*64 + e] = accQ[dd];
    }
    if (t < 64) pbufN[((size_t)bh*8 + st)*64 + t] = nsum;
}

// ---------------------------------------------------------------------------
// reduce 8 partials + init terms -> meml/memq/nrmt
// ---------------------------------------------------------------------------
__global__ __launch_bounds__(256)
void memreduce_kernel(const float* __restrict__ pbufL, const float* __restrict__ pbufQ,
                      const float* __restrict__ pbufN,
                      const void* __restrict__ meml_in, const void* __restrict__ memq_in,
                      const void* __restrict__ norm_in, const int* __restrict__ flagp,
                      float* __restrict__ meml, float* __restrict__ memq,
                      float* __restrict__ nrmt) {
    int f = *flagp;
    size_t gi = (size_t)blockIdx.x * 256 + threadIdx.x;   // < 128*4096
    int bh = (int)(gi >> 12);
    int i  = (int)(gi & 4095);
    float sL = dread(meml_in, gi, f);
    float sQ = dread(memq_in, gi, f);
    #pragma unroll
    for (int p = 0; p < 8; ++p) {
        sL += pbufL[((size_t)bh*8 + p)*4096 + i];
        sQ += pbufQ[((size_t)bh*8 + p)*4096 + i];
    }
    meml[gi] = sL;
    memq[gi] = sQ;
    if (i < 64) {
        float sN = dread(norm_in, (size_t)bh*64 + i, f);
        #pragma unroll
        for (int p = 0; p < 8; ++p) sN += pbufN[((size_t)bh*8 + p)*64 + i];
        nrmt[(size_t)bh*64 + i] = sN;
    }
}

// ---------------------------------------------------------------------------
// memory readout + per-row gate -> memcomb (bf16, parked in d_out)
// S-split: grid (B*H, S/64); each block does 64 rows, Ml/Mq staged once.
// No in-loop barriers: sq[w][*] is private to wave w.
// ---------------------------------------------------------------------------
__global__ __launch_bounds__(256)
void memout_kernel(const bf16* __restrict__ xq, const float* __restrict__ meml,
                   const float* __restrict__ memq, const float* __restrict__ nrmt,
                   const void* __restrict__ gw, const void* __restrict__ gb,
                   const int* __restrict__ flagp, bf16* __restrict__ memcomb) {
    int f = *flagp;
    __shared__ float Ml[64][64];
    __shared__ float Mq[64][64];
    __shared__ float nr[64];
    __shared__ float gwv[64];
    __shared__ float sq[4][64];
    int bh = blockIdx.x;
    int st = blockIdx.y;                 // s-tile of 64 rows
    int b = bh >> 5, h = bh & 31;
    int t = threadIdx.x;
    int w = t >> 6, lane = t & 63;
    size_t mb = (size_t)bh * 4096;
    const floatx4* mlv = (const floatx4*)(meml + mb);
    const floatx4* mqv = (const floatx4*)(memq + mb);
    floatx4* Mlv = (floatx4*)&Ml[0][0];
    floatx4* Mqv = (floatx4*)&Mq[0][0];
    for (int i = t; i < 1024; i += 256) {
        Mlv[i] = mlv[i];
        Mqv[i] = mqv[i];
    }
    if (t < 64) { nr[t] = nrmt[(size_t)bh*64 + t]; gwv[t] = dread(gw, t, f); }
    float gbv = dread(gb, 0, f);
    __syncthreads();
    for (int i = 0; i < 16; ++i) {
        int s = st*64 + i*4 + w;
        float x = b2f(xq[((size_t)(b*S_ + s))*DIM_ + h*64 + lane]);
        float sqv = elu1f(x);
        sq[w][lane] = sqv;
        float dv = sqv * nr[lane];
        for (int off = 32; off; off >>= 1) dv += __shfl_xor(dv, off, 64);
        float mo = 0.f, qmo = 0.f;
        #pragma unroll
        for (int d = 0; d < 64; ++d) {
            float sqd = sq[w][d];
            mo  += sqd * Ml[d][lane];
            qmo += sqd * Mq[d][lane];
        }
        float inv = 1.f / dv;
        mo *= inv; qmo *= inv;
        float gqv = qmo * gwv[lane];
        for (int off = 32; off; off >>= 1) gqv += __shfl_xor(gqv, off, 64);
        float gq = sigmoidf(gqv + gbv);
        memcomb[(((size_t)bh)*S_ + s)*64 + lane] = __float2bfloat16(mo + gq * qmo);
    }
}

// ---------------------------------------------------------------------------
// in-place RoPE on bf16 workspaces (xq and xk in one launch via blockIdx.y)
// ---------------------------------------------------------------------------
__global__ void rope_kernel(bf16* __restrict__ xq, bf16* __restrict__ xk,
                            const void* __restrict__ fcos,
                            const void* __restrict__ fsin,
                            const int* __restrict__ flagp) {
    int f = *flagp;
    bf16* buf = blockIdx.y ? xk : xq;
    int pid = (blockIdx.x * 256 + threadIdx.x) * 4;  // first pair index
    int cp = pid & 1023;          // pair within row (multiple of 4)
    int m  = pid >> 10;           // row (b*S + s)
    int s  = m & (S_-1);
    int p  = cp & 31;             // pair within head (multiple of 4)
    size_t idx = (size_t)m * DIM_ + cp*2;
    short8 v = *(const short8*)(buf + idx);
    short8 o;
    #pragma unroll
    for (int j = 0; j < 4; ++j) {
        float c  = dread(fcos, s*32 + p + j, f);
        float sn = dread(fsin, s*32 + p + j, f);
        float a = b2f(((bf16*)&v)[2*j]);
        float b = b2f(((bf16*)&v)[2*j+1]);
        ((bf16*)&o)[2*j]   = __float2bfloat16(a*c - b*sn);
        ((bf16*)&o)[2*j+1] = __float2bfloat16(a*sn + b*c);
    }
    *(short8*)(buf + idx) = o;
}

// ---------------------------------------------------------------------------
// V transpose: vtg[(b*H+h)*64 + d][s] = xv[(b*S+s)][h*64+d]
// 64x64 tiles via LDS with xor-swizzled columns to dodge bank conflicts.
// ---------------------------------------------------------------------------
__global__ __launch_bounds__(256)
void vtrans_kernel(const bf16* __restrict__ xv, bf16* __restrict__ vtg) {
    __shared__ bf16 tile[64*72];
    int bh = blockIdx.x;
    int b = bh >> 5;
    int s0 = blockIdx.y * 64;
    int tid = threadIdx.x;
    // load 64 s-rows x 64 d, swizzle column-blocks by row
    for (int it = tid; it < 512; it += 256) {
        int row = it >> 3, blk = it & 7;
        short8 val = *(const short8*)(xv + (size_t)(b*S_ + s0 + row)*DIM_
                                      + (bh & 31)*64 + blk*8);
        *(short8*)(tile + row*72 + ((blk ^ (row & 7))*8)) = val;
    }
    __syncthreads();
    // write d-rows: thread (d = it>>3, s-block = it&7) gathers 8 s for fixed d
    for (int it = tid; it < 512; it += 256) {
        int d = it >> 3, sb = (it & 7)*8;
        short8 o;
        #pragma unroll
        for (int i = 0; i < 8; ++i) {
            int s = sb + i;
            o[i] = *(const short*)(tile + s*72 + (((d>>3) ^ (s & 7))*8) + (d & 7));
        }
        *(short8*)(vtg + ((size_t)bh*64 + d)*S_ + s0 + sb) = o;
    }
}

// ---------------------------------------------------------------------------
// MFMA flash attention + gate-combine epilogue.
// Block: (b,h,64-row Q-tile); 4 waves x 16 Q-rows. K-tiles of 64.
// XCD-grouped blockIdx; T14 reg-prefetch of next K/V tile; Ps XOR-swizzle;
// setprio around MFMA clusters.
// ---------------------------------------------------------------------------
__global__ __launch_bounds__(256)
void attn_mfma_kernel(const bf16* __restrict__ qr, const bf16* __restrict__ kr,
                      const bf16* __restrict__ vtg, const bf16* __restrict__ memcomb,
                      const void* __restrict__ gate, const int* __restrict__ flagp,
                      bf16* __restrict__ outc) {
    __shared__ bf16 Qs[64*72];
    __shared__ bf16 Ks[64*72];
    __shared__ bf16 Vt[64*72];   // [d][kk]
    __shared__ bf16 Ps[4][16*72];
    // XCD swizzle: group all 16 q-tiles of a (b,h) onto one XCD (assumes RR %8)
    int bid0 = blockIdx.x;
    int bid = ((bid0 & 7) << 8) | (bid0 >> 3);
    int qt = bid & 15;
    int h  = (bid >> 4) & 31;
    int b  = bid >> 9;
    int q0 = qt * 64;
    int tid = threadIdx.x;
    int w = tid >> 6, lane = tid & 63;
    int quad = lane >> 4, r16 = lane & 15;

    // stage Q tile + K/V tile 0
    for (int it = tid; it < 512; it += 256) {
        int row = it >> 3, c8 = (it & 7)*8;
        *(short8*)(Qs + row*72 + c8) =
            *(const short8*)(qr + (size_t)(b*S_ + q0 + row)*DIM_ + h*64 + c8);
        *(short8*)(Ks + row*72 + c8) =
            *(const short8*)(kr + (size_t)(b*S_ + row)*DIM_ + h*64 + c8);
        *(short8*)(Vt + row*72 + c8) =
            *(const short8*)(vtg + ((size_t)(b*H_ + h)*64 + row)*S_ + c8);
    }
    __syncthreads();
    short8 qf[2];
    #pragma unroll
    for (int kb = 0; kb < 2; ++kb)
        qf[kb] = *(const short8*)(Qs + (w*16 + r16)*72 + kb*32 + quad*8);

    float mrow[4] = {-1e30f,-1e30f,-1e30f,-1e30f};
    float lrow[4] = {0.f,0.f,0.f,0.f};
    floatx4 Ox[4];
    #pragma unroll
    for (int db = 0; db < 4; ++db) Ox[db] = (floatx4){0.f,0.f,0.f,0.f};

    // prefetch addressing (two 16B chunks per thread per array)
    int prow0 = tid >> 3, pc8 = (tid & 7)*8;   // rows 0..31
    int prow1 = prow0 + 32;                     // rows 32..63

    int ntiles = qt + 1;
    for (int kt = 0; kt < ntiles; ++kt) {
        int k0 = kt * 64;
        // T14: issue next tile's global loads into regs (latency hides under compute)
        short8 kn0, kn1, vn0, vn1;
        bool pre = (kt + 1 < ntiles);
        if (pre) {
            int k0n = k0 + 64;
            kn0 = *(const short8*)(kr + (size_t)(b*S_ + k0n + prow0)*DIM_ + h*64 + pc8);
            kn1 = *(const short8*)(kr + (size_t)(b*S_ + k0n + prow1)*DIM_ + h*64 + pc8);
            vn0 = *(const short8*)(vtg + ((size_t)(b*H_ + h)*64 + prow0)*S_ + k0n + pc8);
            vn1 = *(const short8*)(vtg + ((size_t)(b*H_ + h)*64 + prow1)*S_ + k0n + pc8);
        }

        // S strip: 16 q-rows x 64 k-cols per wave
        floatx4 Sbv[4];
        __builtin_amdgcn_s_setprio(1);
        #pragma unroll
        for (int nb = 0; nb < 4; ++nb) {
            floatx4 a = (floatx4){0.f,0.f,0.f,0.f};
            #pragma unroll
            for (int kb = 0; kb < 2; ++kb) {
                short8 kf = *(const short8*)(Ks + (nb*16 + r16)*72 + kb*32 + quad*8);
                a = __builtin_amdgcn_mfma_f32_16x16x32_bf16(qf[kb], kf, a, 0, 0, 0);
            }
            Sbv[nb] = a;
        }
        __builtin_amdgcn_s_setprio(0);
        // scale + causal mask
        float S4[4][4];
        #pragma unroll
        for (int nb = 0; nb < 4; ++nb)
            #pragma unroll
            for (int reg = 0; reg < 4; ++reg) {
                int qg = q0 + w*16 + quad*4 + reg;
                int kg = k0 + nb*16 + r16;
                float s = Sbv[nb][reg] * 0.125f;
                S4[nb][reg] = (kg > qg) ? -1e30f : s;
            }
        // online softmax (rows live across the 16 lanes of a quad)
        float alpha[4];
        #pragma unroll
        for (int reg = 0; reg < 4; ++reg) {
            float mx = fmaxf(fmaxf(S4[0][reg], S4[1][reg]),
                             fmaxf(S4[2][reg], S4[3][reg]));
            mx = fmaxf(mx, __shfl_xor(mx, 1, 64));
            mx = fmaxf(mx, __shfl_xor(mx, 2, 64));
            mx = fmaxf(mx, __shfl_xor(mx, 4, 64));
            mx = fmaxf(mx, __shfl_xor(mx, 8, 64));
            float mn = fmaxf(mrow[reg], mx);
            alpha[reg] = __expf(mrow[reg] - mn);
            mrow[reg] = mn;
            float rs = 0.f;
            #pragma unroll
            for (int nb = 0; nb < 4; ++nb) {
                float p = __expf(S4[nb][reg] - mn);
                S4[nb][reg] = p;
                rs += p;
            }
            rs += __shfl_xor(rs, 1, 64);
            rs += __shfl_xor(rs, 2, 64);
            rs += __shfl_xor(rs, 4, 64);
            rs += __shfl_xor(rs, 8, 64);
            lrow[reg] = lrow[reg]*alpha[reg] + rs;
        }
        // P -> LDS (C-layout write), XOR-swizzled cols for rows>=8 (bank-split)
        #pragma unroll
        for (int nb = 0; nb < 4; ++nb)
            #pragma unroll
            for (int reg = 0; reg < 4; ++reg)
                Ps[w][(quad*4 + reg)*72 + ((nb*16 + r16) ^ ((quad & 2) * 8))] =
                    __float2bfloat16(S4[nb][reg]);
        short8 pf[2];
        #pragma unroll
        for (int kb = 0; kb < 2; ++kb)
            pf[kb] = *(const short8*)(&Ps[w][0] + r16*72 +
                                      ((kb*32 + quad*8) ^ ((r16 & 8) << 1)));
        // O = O*alpha + P @ V
        #pragma unroll
        for (int db = 0; db < 4; ++db) {
            #pragma unroll
            for (int reg = 0; reg < 4; ++reg) Ox[db][reg] *= alpha[reg];
        }
        __builtin_amdgcn_s_setprio(1);
        #pragma unroll
        for (int db = 0; db < 4; ++db) {
            #pragma unroll
            for (int kb = 0; kb < 2; ++kb) {
                short8 vf = *(const short8*)(Vt + (db*16 + r16)*72 + kb*32 + quad*8);
                Ox[db] = __builtin_amdgcn_mfma_f32_16x16x32_bf16(pf[kb], vf, Ox[db], 0, 0, 0);
            }
        }
        __builtin_amdgcn_s_setprio(0);
        __syncthreads();   // all reads of Ks/Vt complete
        if (pre) {
            *(short8*)(Ks + prow0*72 + pc8) = kn0;
            *(short8*)(Ks + prow1*72 + pc8) = kn1;
            *(short8*)(Vt + prow0*72 + pc8) = vn0;
            *(short8*)(Vt + prow1*72 + pc8) = vn1;
        }
        __syncthreads();   // staged tile visible
    }

    int f = *flagp;
    float g = sigmoidf(dread(gate, h, f));
    #pragma unroll
    for (int db = 0; db < 4; ++db)
        #pragma unroll
        for (int reg = 0; reg < 4; ++reg) {
            int qg = q0 + w*16 + quad*4 + reg;
            int d  = db*16 + r16;
            float attn = Ox[db][reg] / lrow[reg];
            float comb = b2f(memcomb[((size_t)(b*H_ + h)*S_ + qg)*64 + d]);
            outc[(size_t)(b*S_ + qg)*DIM_ + h*64 + d] =
                __float2bfloat16(g*comb + (1.f - g)*attn);
        }
}

// ---------------------------------------------------------------------------
extern "C" void kernel_launch(void* const* d_in, const int* in_sizes, int n_in,
                              void* d_out, int out_size, void* d_ws, size_t ws_size,
                              hipStream_t stream) {
    const void* x        = d_in[0];
    const void* pq       = d_in[1];
    const void* cache_k  = d_in[2];
    const void* cache_v  = d_in[3];
    const void* mem_long = d_in[4];
    const void* mem_qry  = d_in[5];
    const void* norm_t   = d_in[6];
    const void* fcos     = d_in[7];
    const void* fsin     = d_in[8];
    // d_in[9] = mask (unused; causal applied analytically)
    const void* wq  = d_in[10];
    const void* wk  = d_in[11];
    const void* wv  = d_in[12];
    const void* wo  = d_in[13];
    const void* lq1 = d_in[14];
    const void* lq2 = d_in[15];
    const void* lk1 = d_in[16];
    const void* lk2 = d_in[17];
    const void* lv1 = d_in[18];
    const void* lv2 = d_in[19];
    const void* lo1 = d_in[20];
    const void* lo2 = d_in[21];
    const void* gate = d_in[22];
    const void* gmw  = d_in[23];
    const void* gmb  = d_in[24];

    const size_t NBSD = (size_t)BS_ * DIM_;   // 8388608
    const size_t NW   = (size_t)DIM_ * DIM_;  // 4194304
    int*  flag = (int*)d_ws;
    bf16* xb   = (bf16*)((char*)d_ws + 16);   // converted x
    bf16* wbuf = xb + NBSD;                   // fused (W + L2*L1) bf16
    bf16* xq   = wbuf + NW;
    bf16* xk   = xq + NBSD;
    bf16* xv   = xk + NBSD;
    bf16* outc = xv + NBSD;
    bf16* vtg  = outc + NBSD;                 // V transposed: [b,h,d,s]
    float* qsig = (float*)(vtg + NBSD);       // (slot kept; qscore now fused)
    float* meml = qsig + (size_t)B_*H_*S_;
    float* memq = meml + (size_t)B_*H_*HD_*HD_;
    float* nrmt = memq + (size_t)B_*H_*HD_*HD_;
    bf16* memcomb = (bf16*)d_out;   // parked; final GEMM overwrites d_out

    // extra QKV weight buffers OVERLAID on vtg (dead until vtrans; 2*NW==NBSD)
    bf16* wbK = (bf16*)vtg;
    bf16* wbV = wbK + NW;

    // partial buffers OVERLAID on dead regions (timeline-checked):
    // pbufL -> xb region   (xb dead after QKV GEMM)
    // pbufQ -> outc region (outc first written at attn, after memreduce)
    // pbufN -> wbuf region (wbuf dead between QKV GEMM and final wprep)
    float* pbufL = (float*)xb;
    float* pbufQ = (float*)outc;
    float* pbufN = (float*)wbuf;

    dim3 ggrid(DIM_/128, BS_/128);      // (16, 32) final GEMM
    dim3 ggrid3(3*DIM_/128, BS_/128);   // (48, 32) fused QKV GEMM
    dim3 wgrid(DIM_/256, DIM_);         // (8, 2048)
    dim3 wgrid3(DIM_/256, DIM_, 3);     // (8, 2048, 3)

    // 0. dtype detect
    detect_kernel<<<1, 256, 0, stream>>>(x, flag);
    // 1. convert x to bf16 (x8 vectorized)
    convert_kernel<<<(int)(NBSD/2048), 256, 0, stream>>>(x, xb, (int)NBSD, flag);
    // 2. projections: fold low-rank into weights (one launch), fused QKV GEMM
    wprep3_kernel<<<wgrid3, 256, 0, stream>>>(wq, wk, wv, lq1, lk1, lv1,
                                              lq2, lk2, lv2, flag,
                                              wbuf, wbK, wbV);
    gemm_mfma3_kernel<<<ggrid3, 256, 0, stream>>>(xb, wbuf, wbK, wbV, xq, xk, xv);
    // 3. V transpose for MFMA attention (overwrites wbK/wbV region)
    vtrans_kernel<<<dim3(B_*H_, S_/64), 256, 0, stream>>>(xv, vtg);
    // 4+5. memory accumulation (qscore fused): S-split partials + reduce
    mem_kernel<<<dim3(B_*H_, 8), 256, 0, stream>>>(cache_k, cache_v, pq, flag,
                                                   pbufL, pbufQ, pbufN);
    memreduce_kernel<<<(B_*H_*HD_*HD_)/256, 256, 0, stream>>>(
        pbufL, pbufQ, pbufN, mem_long, mem_qry, norm_t, flag, meml, memq, nrmt);
    // 6. memory readout + gate (consumes UN-roped xq); S-split grid
    memout_kernel<<<dim3(B_*H_, S_/64), 256, 0, stream>>>(xq, meml, memq, nrmt,
                                                          gmw, gmb, flag, memcomb);
    // 7. RoPE in place (xq + xk in one launch)
    rope_kernel<<<dim3((BS_*1024)/(256*4), 2), 256, 0, stream>>>(xq, xk, fcos, fsin, flag);
    // 8. MFMA causal attention + combine epilogue
    attn_mfma_kernel<<<B_*H_*(S_/64), 256, 0, stream>>>(xq, xk, vtg, memcomb,
                                                        gate, flag, outc);
    // 9. output projection
    wprep_kernel<<<wgrid, 256, 0, stream>>>(wo, lo1, lo2, flag, wbuf);
    gemm_mfma_kernel<0><<<ggrid, 256, 0, stream>>>(outc, wbuf, flag, d_out);
}

// Round 8
// 772.558 us; speedup vs baseline: 1.0144x; 1.0144x over previous
//
#include <hip/hip_runtime.h>
#include <hip/hip_bf16.h>

typedef __hip_bfloat16 bf16;
typedef __attribute__((ext_vector_type(8))) short short8;
typedef __attribute__((ext_vector_type(4))) float floatx4;

#define B_ 4
#define S_ 1024
#define DIM_ 2048
#define H_ 32
#define HD_ 64
#define R_ 16
#define BS_ (B_*S_)   // 4096

typedef __attribute__((address_space(1))) void GVoid;
typedef __attribute__((address_space(3))) void LVoid;
#define GLDS16(gp, lp) __builtin_amdgcn_global_load_lds((GVoid*)(gp), (LVoid*)(lp), 16, 0, 0)

__device__ __forceinline__ float b2f(bf16 v){ return __bfloat162float(v); }
__device__ __forceinline__ float elu1f(float x){ return x > 0.f ? x + 1.f : __expf(x); }
__device__ __forceinline__ float sigmoidf(float x){ return 1.f/(1.f + __expf(-x)); }
__device__ __forceinline__ float loadf(bf16 v){ return __bfloat162float(v); }
__device__ __forceinline__ float loadf(float v){ return v; }

// dtype-adaptive input read: f=1 -> bf16, f=0 -> fp32 (uniform branch).
__device__ __forceinline__ float dread(const void* p, size_t i, int f){
    float r;
    if (f) r = __bfloat162float(((const bf16*)p)[i]);
    else   r = ((const float*)p)[i];
    return r;
}
__device__ __forceinline__ void dwrite(void* p, size_t i, float v, int f){
    if (f) ((bf16*)p)[i] = __float2bfloat16(v);
    else   ((float*)p)[i] = v;
}

// ---------------------------------------------------------------------------
// dtype detect (same every call; graph-safe)
// ---------------------------------------------------------------------------
__global__ void detect_kernel(const void* __restrict__ x, int* __restrict__ flag){
    __shared__ int cnt[256];
    int t = threadIdx.x;
    int c = 0;
    for (int i = t; i < 4096; i += 256){
        float v = __bfloat162float(((const bf16*)x)[i]);
        float a = fabsf(v);
        if (a > 1e-3f && a < 1e3f) c++;
    }
    cnt[t] = c;
    __syncthreads();
    if (t == 0){
        int s = 0;
        for (int i = 0; i < 256; ++i) s += cnt[i];
        *flag = (s > 3686) ? 1 : 0;
    }
}

// ---------------------------------------------------------------------------
// convert input (fp32 or bf16 per flag) -> bf16 workspace copy, x8 vectorized
// ---------------------------------------------------------------------------
__global__ void convert_kernel(const void* __restrict__ src, bf16* __restrict__ dst,
                               int n, const int* __restrict__ flagp){
    int i = (blockIdx.x * 256 + threadIdx.x) * 8;
    if (i >= n) return;
    short8 o;
    if (*flagp){
        o = *(const short8*)((const bf16*)src + i);
    } else {
        const float* s = (const float*)src + i;
        float4 v0 = *(const float4*)(s);
        float4 v1 = *(const float4*)(s + 4);
        ((bf16*)&o)[0] = __float2bfloat16(v0.x);
        ((bf16*)&o)[1] = __float2bfloat16(v0.y);
        ((bf16*)&o)[2] = __float2bfloat16(v0.z);
        ((bf16*)&o)[3] = __float2bfloat16(v0.w);
        ((bf16*)&o)[4] = __float2bfloat16(v1.x);
        ((bf16*)&o)[5] = __float2bfloat16(v1.y);
        ((bf16*)&o)[6] = __float2bfloat16(v1.z);
        ((bf16*)&o)[7] = __float2bfloat16(v1.w);
    }
    *(short8*)(dst + i) = o;
}

// ---------------------------------------------------------------------------
// fused weight prep: W'[n,k] = W[n,k] + sum_r L2[n,r] * L1[r,k]   -> bf16
// ---------------------------------------------------------------------------
template<typename T>
__device__ __forceinline__ void wprep_body(const T* __restrict__ W,
                                           const T* __restrict__ L1,
                                           const T* __restrict__ L2,
                                           bf16* __restrict__ dst){
    int n = blockIdx.y;
    int k = blockIdx.x * 256 + threadIdx.x;
    size_t nk = (size_t)n * DIM_ + k;
    float acc = loadf(W[nk]);
    #pragma unroll
    for (int r = 0; r < 16; ++r)
        acc += loadf(L2[n*16 + r]) * loadf(L1[(size_t)r*DIM_ + k]);
    dst[nk] = __float2bfloat16(acc);
}
__global__ __launch_bounds__(256)
void wprep_kernel(const void* __restrict__ W, const void* __restrict__ L1,
                  const void* __restrict__ L2, const int* __restrict__ flagp,
                  bf16* __restrict__ dst){
    if (*flagp) wprep_body((const bf16*)W, (const bf16*)L1, (const bf16*)L2, dst);
    else        wprep_body((const float*)W, (const float*)L1, (const float*)L2, dst);
}

// one launch for all 3 QKV weights: blockIdx.z selects the triplet
__global__ __launch_bounds__(256)
void wprep3_kernel(const void* __restrict__ W0, const void* __restrict__ W1,
                   const void* __restrict__ W2,
                   const void* __restrict__ L1q, const void* __restrict__ L1k,
                   const void* __restrict__ L1v,
                   const void* __restrict__ L2q, const void* __restrict__ L2k,
                   const void* __restrict__ L2v,
                   const int* __restrict__ flagp,
                   bf16* __restrict__ d0, bf16* __restrict__ d1,
                   bf16* __restrict__ d2){
    int z = blockIdx.z;
    const void* W  = (z==0) ? W0 : (z==1) ? W1 : W2;
    const void* L1 = (z==0) ? L1q : (z==1) ? L1k : L1v;
    const void* L2 = (z==0) ? L2q : (z==1) ? L2k : L2v;
    bf16* dst = (z==0) ? d0 : (z==1) ? d1 : d2;
    if (*flagp) wprep_body((const bf16*)W, (const bf16*)L1, (const bf16*)L2, dst);
    else        wprep_body((const float*)W, (const float*)L1, (const float*)L2, dst);
}

// ---------------------------------------------------------------------------
// MFMA GEMM: C[m,n] = sum_k A[m,k]*Bw[n,k]
// m97 single-buffer flow, BK=64 via 2x in-place unroll: two 128x32 sub-tiles
// staged per barrier pair (same per-sub-tile layout/addressing as BK=32).
// ---------------------------------------------------------------------------
template<int CMODE>   // 1: bf16 ws out; 0: dual-dtype d_out
__global__ __launch_bounds__(256)
void gemm_mfma_kernel(const bf16* __restrict__ A, const bf16* __restrict__ Bw,
                      const int* __restrict__ flagp, void* __restrict__ C) {
    __shared__ bf16 Als[2*128*32];
    __shared__ bf16 Bls[2*128*32];
    int tid = threadIdx.x;
    int w = tid >> 6, lane = tid & 63;
    int wr = w >> 1, wc = w & 1;
    int rm0 = blockIdx.y * 128;
    int cn0 = blockIdx.x * 128;

    const bf16* gA = A  + (size_t)(rm0 + w*32 + (lane>>2)) * DIM_ + (lane&3)*8;
    const bf16* gB = Bw + (size_t)(cn0 + w*32 + (lane>>2)) * DIM_ + (lane&3)*8;
    bf16* lA0  = Als + (w*32)*32;
    bf16* lA1  = Als + (w*32+16)*32;
    bf16* lB0  = Bls + (w*32)*32;
    bf16* lB1  = Bls + (w*32+16)*32;
    bf16* lA0b = lA0 + 4096;
    bf16* lA1b = lA1 + 4096;
    bf16* lB0b = lB0 + 4096;
    bf16* lB1b = lB1 + 4096;

    floatx4 acc[4][4];
    #pragma unroll
    for (int i = 0; i < 4; ++i)
        #pragma unroll
        for (int j = 0; j < 4; ++j) acc[i][j] = (floatx4){0.f,0.f,0.f,0.f};

    int aoff[4], boff[4];
    #pragma unroll
    for (int i = 0; i < 4; ++i) {
        aoff[i] = (wr*64 + i*16 + (lane&15))*32 + (lane>>4)*8;
        boff[i] = (wc*64 + i*16 + (lane&15))*32 + (lane>>4)*8;
    }

    for (int kk = 0; kk < DIM_; kk += 64) {
        GLDS16(gA + kk,                  lA0);
        GLDS16(gA + 16*DIM_ + kk,        lA1);
        GLDS16(gB + kk,                  lB0);
        GLDS16(gB + 16*DIM_ + kk,        lB1);
        GLDS16(gA + kk + 32,             lA0b);
        GLDS16(gA + 16*DIM_ + kk + 32,   lA1b);
        GLDS16(gB + kk + 32,             lB0b);
        GLDS16(gB + 16*DIM_ + kk + 32,   lB1b);
        __syncthreads();
        short8 af[4], bf_[4];
        #pragma unroll
        for (int i = 0; i < 4; ++i) {
            af[i]  = *(const short8*)(Als + aoff[i]);
            bf_[i] = *(const short8*)(Bls + boff[i]);
        }
        #pragma unroll
        for (int i = 0; i < 4; ++i)
            #pragma unroll
            for (int j = 0; j < 4; ++j)
                acc[i][j] = __builtin_amdgcn_mfma_f32_16x16x32_bf16(
                    af[i], bf_[j], acc[i][j], 0, 0, 0);
        #pragma unroll
        for (int i = 0; i < 4; ++i) {
            af[i]  = *(const short8*)(Als + 4096 + aoff[i]);
            bf_[i] = *(const short8*)(Bls + 4096 + boff[i]);
        }
        #pragma unroll
        for (int i = 0; i < 4; ++i)
            #pragma unroll
            for (int j = 0; j < 4; ++j)
                acc[i][j] = __builtin_amdgcn_mfma_f32_16x16x32_bf16(
                    af[i], bf_[j], acc[i][j], 0, 0, 0);
        __syncthreads();
    }

    int f = (CMODE==0) ? *flagp : 1;
    #pragma unroll
    for (int i = 0; i < 4; ++i) {
        #pragma unroll
        for (int reg = 0; reg < 4; ++reg) {
            int m_loc = wr*64 + i*16 + (lane>>4)*4 + reg;
            #pragma unroll
            for (int j = 0; j < 4; ++j) {
                int n_loc = wc*64 + j*16 + (lane&15);
                float val = acc[i][j][reg];
                size_t idx = (size_t)(rm0 + m_loc) * DIM_ + cn0 + n_loc;
                if (CMODE==1) ((bf16*)C)[idx] = __float2bfloat16(val);
                else          dwrite(C, idx, val, f);
            }
        }
    }
}

// fused QKV GEMM: grid (48, 32); blockIdx.x>>4 selects weight/output pair.
// Same BK=64 2x-unrolled single-buffer structure.
__global__ __launch_bounds__(256)
void gemm_mfma3_kernel(const bf16* __restrict__ A,
                       const bf16* __restrict__ B0, const bf16* __restrict__ B1,
                       const bf16* __restrict__ B2,
                       bf16* __restrict__ C0, bf16* __restrict__ C1,
                       bf16* __restrict__ C2) {
    __shared__ bf16 Als[2*128*32];
    __shared__ bf16 Bls[2*128*32];
    int tid = threadIdx.x;
    int w = tid >> 6, lane = tid & 63;
    int wr = w >> 1, wc = w & 1;
    int rm0 = blockIdx.y * 128;
    int wz  = blockIdx.x >> 4;
    int cn0 = (blockIdx.x & 15) * 128;
    const bf16* Bw = (wz==0) ? B0 : (wz==1) ? B1 : B2;
    bf16* C        = (wz==0) ? C0 : (wz==1) ? C1 : C2;

    const bf16* gA = A  + (size_t)(rm0 + w*32 + (lane>>2)) * DIM_ + (lane&3)*8;
    const bf16* gB = Bw + (size_t)(cn0 + w*32 + (lane>>2)) * DIM_ + (lane&3)*8;
    bf16* lA0  = Als + (w*32)*32;
    bf16* lA1  = Als + (w*32+16)*32;
    bf16* lB0  = Bls + (w*32)*32;
    bf16* lB1  = Bls + (w*32+16)*32;
    bf16* lA0b = lA0 + 4096;
    bf16* lA1b = lA1 + 4096;
    bf16* lB0b = lB0 + 4096;
    bf16* lB1b = lB1 + 4096;

    floatx4 acc[4][4];
    #pragma unroll
    for (int i = 0; i < 4; ++i)
        #pragma unroll
        for (int j = 0; j < 4; ++j) acc[i][j] = (floatx4){0.f,0.f,0.f,0.f};

    int aoff[4], boff[4];
    #pragma unroll
    for (int i = 0; i < 4; ++i) {
        aoff[i] = (wr*64 + i*16 + (lane&15))*32 + (lane>>4)*8;
        boff[i] = (wc*64 + i*16 + (lane&15))*32 + (lane>>4)*8;
    }

    for (int kk = 0; kk < DIM_; kk += 64) {
        GLDS16(gA + kk,                  lA0);
        GLDS16(gA + 16*DIM_ + kk,        lA1);
        GLDS16(gB + kk,                  lB0);
        GLDS16(gB + 16*DIM_ + kk,        lB1);
        GLDS16(gA + kk + 32,             lA0b);
        GLDS16(gA + 16*DIM_ + kk + 32,   lA1b);
        GLDS16(gB + kk + 32,             lB0b);
        GLDS16(gB + 16*DIM_ + kk + 32,   lB1b);
        __syncthreads();
        short8 af[4], bf_[4];
        #pragma unroll
        for (int i = 0; i < 4; ++i) {
            af[i]  = *(const short8*)(Als + aoff[i]);
            bf_[i] = *(const short8*)(Bls + boff[i]);
        }
        #pragma unroll
        for (int i = 0; i < 4; ++i)
            #pragma unroll
            for (int j = 0; j < 4; ++j)
                acc[i][j] = __builtin_amdgcn_mfma_f32_16x16x32_bf16(
                    af[i], bf_[j], acc[i][j], 0, 0, 0);
        #pragma unroll
        for (int i = 0; i < 4; ++i) {
            af[i]  = *(const short8*)(Als + 4096 + aoff[i]);
            bf_[i] = *(const short8*)(Bls + 4096 + boff[i]);
        }
        #pragma unroll
        for (int i = 0; i < 4; ++i)
            #pragma unroll
            for (int j = 0; j < 4; ++j)
                acc[i][j] = __builtin_amdgcn_mfma_f32_16x16x32_bf16(
                    af[i], bf_[j], acc[i][j], 0, 0, 0);
        __syncthreads();
    }

    #pragma unroll
    for (int i = 0; i < 4; ++i) {
        #pragma unroll
        for (int reg = 0; reg < 4; ++reg) {
            int m_loc = wr*64 + i*16 + (lane>>4)*4 + reg;
            #pragma unroll
            for (int j = 0; j < 4; ++j) {
                int n_loc = wc*64 + j*16 + (lane&15);
                size_t idx = (size_t)(rm0 + m_loc) * DIM_ + cn0 + n_loc;
                C[idx] = __float2bfloat16(acc[i][j][reg]);
            }
        }
    }
}

// ---------------------------------------------------------------------------
// per (b,h,s-tile): PARTIAL mem_l/mem_q outer-product accumulation + nrm.
// Grid (B*H, 8); each block covers 128 s-rows; partials to pbuf*.
// qscore FUSED: wave w owns row sl=w; dot(pq, raw_k) via wave shfl-reduce.
// ---------------------------------------------------------------------------
__global__ __launch_bounds__(256)
void mem_kernel(const void* __restrict__ ck, const void* __restrict__ cv,
                const void* __restrict__ pq,
                const int* __restrict__ flagp,
                float* __restrict__ pbufL, float* __restrict__ pbufQ,
                float* __restrict__ pbufN) {
    int f = *flagp;
    __shared__ float ks[4][64], vs[4][64], fv[4][64];
    int bh = blockIdx.x;
    int st = blockIdx.y;                 // s-tile of 128 rows
    int b = bh >> 5, h = bh & 31;
    int t = threadIdx.x;
    int e = t & 63;
    int dg = t >> 6;
    float pqd = dread(pq, ((size_t)b*H_ + h)*HD_ + e, f);
    float accL[16] = {};
    float accQ[16] = {};
    float nsum = 0.f;
    int sbase = st * 128;
    for (int s0 = 0; s0 < 128; s0 += 4) {
        int sl = t >> 6, d = t & 63;
        int s = sbase + s0 + sl;
        size_t base = (((size_t)b*S_ + s)*H_ + h)*HD_ + d;
        float kraw = dread(ck, base, f);
        float kv = elu1f(kraw);
        float vv = dread(cv, base, f);
        float dot = pqd * kraw;
        for (int off = 32; off; off >>= 1) dot += __shfl_xor(dot, off, 64);
        float sg = sigmoidf(dot * 0.125f);
        ks[sl][d] = kv;
        vs[sl][d] = vv;
        fv[sl][d] = vv * sg;
        __syncthreads();
        #pragma unroll
        for (int s2 = 0; s2 < 4; ++s2) {
            float ve = vs[s2][e];
            float fe = fv[s2][e];
            #pragma unroll
            for (int dd = 0; dd < 16; ++dd) {
                float kk = ks[s2][dg*16 + dd];
                accL[dd] += kk * ve;
                accQ[dd] += kk * fe;
            }
        }
        if (t < 64) {
            #pragma unroll
            for (int s2 = 0; s2 < 4; ++s2) nsum += ks[s2][t];
        }
        __syncthreads();
    }
    size_t pb = ((size_t)bh*8 + st) * 4096;
    #pragma unroll
    for (int dd = 0; dd < 16; ++dd) {
        int d = dg*16 + dd;
        pbufL[pb + d*64 + e] = accL[dd];
        pbufQ[pb + d*64 + e] = accQ[dd];
    }
    if (t < 64) pbufN[((size_t)bh*8 + st)*64 + t] = nsum;
}

// ---------------------------------------------------------------------------
// reduce 8 partials + init terms -> meml/memq/nrmt
// ---------------------------------------------------------------------------
__global__ __launch_bounds__(256)
void memreduce_kernel(const float* __restrict__ pbufL, const float* __restrict__ pbufQ,
                      const float* __restrict__ pbufN,
                      const void* __restrict__ meml_in, const void* __restrict__ memq_in,
                      const void* __restrict__ norm_in, const int* __restrict__ flagp,
                      float* __restrict__ meml, float* __restrict__ memq,
                      float* __restrict__ nrmt) {
    int f = *flagp;
    size_t gi = (size_t)blockIdx.x * 256 + threadIdx.x;   // < 128*4096
    int bh = (int)(gi >> 12);
    int i  = (int)(gi & 4095);
    float sL = dread(meml_in, gi, f);
    float sQ = dread(memq_in, gi, f);
    #pragma unroll
    for (int p = 0; p < 8; ++p) {
        sL += pbufL[((size_t)bh*8 + p)*4096 + i];
        sQ += pbufQ[((size_t)bh*8 + p)*4096 + i];
    }
    meml[gi] = sL;
    memq[gi] = sQ;
    if (i < 64) {
        float sN = dread(norm_in, (size_t)bh*64 + i, f);
        #pragma unroll
        for (int p = 0; p < 8; ++p) sN += pbufN[((size_t)bh*8 + p)*64 + i];
        nrmt[(size_t)bh*64 + i] = sN;
    }
}

// ---------------------------------------------------------------------------
// memory readout + per-row gate -> memcomb (bf16, parked in d_out)
// S-split: grid (B*H, S/64); each block does 64 rows, Ml/Mq staged once.
// No in-loop barriers: sq[w][*] is private to wave w.
// ---------------------------------------------------------------------------
__global__ __launch_bounds__(256)
void memout_kernel(const bf16* __restrict__ xq, const float* __restrict__ meml,
                   const float* __restrict__ memq, const float* __restrict__ nrmt,
                   const void* __restrict__ gw, const void* __restrict__ gb,
                   const int* __restrict__ flagp, bf16* __restrict__ memcomb) {
    int f = *flagp;
    __shared__ float Ml[64][64];
    __shared__ float Mq[64][64];
    __shared__ float nr[64];
    __shared__ float gwv[64];
    __shared__ float sq[4][64];
    int bh = blockIdx.x;
    int st = blockIdx.y;                 // s-tile of 64 rows
    int b = bh >> 5, h = bh & 31;
    int t = threadIdx.x;
    int w = t >> 6, lane = t & 63;
    size_t mb = (size_t)bh * 4096;
    const floatx4* mlv = (const floatx4*)(meml + mb);
    const floatx4* mqv = (const floatx4*)(memq + mb);
    floatx4* Mlv = (floatx4*)&Ml[0][0];
    floatx4* Mqv = (floatx4*)&Mq[0][0];
    for (int i = t; i < 1024; i += 256) {
        Mlv[i] = mlv[i];
        Mqv[i] = mqv[i];
    }
    if (t < 64) { nr[t] = nrmt[(size_t)bh*64 + t]; gwv[t] = dread(gw, t, f); }
    float gbv = dread(gb, 0, f);
    __syncthreads();
    for (int i = 0; i < 16; ++i) {
        int s = st*64 + i*4 + w;
        float x = b2f(xq[((size_t)(b*S_ + s))*DIM_ + h*64 + lane]);
        float sqv = elu1f(x);
        sq[w][lane] = sqv;
        float dv = sqv * nr[lane];
        for (int off = 32; off; off >>= 1) dv += __shfl_xor(dv, off, 64);
        float mo = 0.f, qmo = 0.f;
        #pragma unroll
        for (int d = 0; d < 64; ++d) {
            float sqd = sq[w][d];
            mo  += sqd * Ml[d][lane];
            qmo += sqd * Mq[d][lane];
        }
        float inv = 1.f / dv;
        mo *= inv; qmo *= inv;
        float gqv = qmo * gwv[lane];
        for (int off = 32; off; off >>= 1) gqv += __shfl_xor(gqv, off, 64);
        float gq = sigmoidf(gqv + gbv);
        memcomb[(((size_t)bh)*S_ + s)*64 + lane] = __float2bfloat16(mo + gq * qmo);
    }
}

// ---------------------------------------------------------------------------
// in-place RoPE on bf16 workspaces (xq and xk in one launch via blockIdx.y)
// ---------------------------------------------------------------------------
__global__ void rope_kernel(bf16* __restrict__ xq, bf16* __restrict__ xk,
                            const void* __restrict__ fcos,
                            const void* __restrict__ fsin,
                            const int* __restrict__ flagp) {
    int f = *flagp;
    bf16* buf = blockIdx.y ? xk : xq;
    int pid = (blockIdx.x * 256 + threadIdx.x) * 4;  // first pair index
    int cp = pid & 1023;          // pair within row (multiple of 4)
    int m  = pid >> 10;           // row (b*S + s)
    int s  = m & (S_-1);
    int p  = cp & 31;             // pair within head (multiple of 4)
    size_t idx = (size_t)m * DIM_ + cp*2;
    short8 v = *(const short8*)(buf + idx);
    short8 o;
    #pragma unroll
    for (int j = 0; j < 4; ++j) {
        float c  = dread(fcos, s*32 + p + j, f);
        float sn = dread(fsin, s*32 + p + j, f);
        float a = b2f(((bf16*)&v)[2*j]);
        float b = b2f(((bf16*)&v)[2*j+1]);
        ((bf16*)&o)[2*j]   = __float2bfloat16(a*c - b*sn);
        ((bf16*)&o)[2*j+1] = __float2bfloat16(a*sn + b*c);
    }
    *(short8*)(buf + idx) = o;
}

// ---------------------------------------------------------------------------
// V transpose: vtg[(b*H+h)*64 + d][s] = xv[(b*S+s)][h*64+d]
// 64x64 tiles via LDS with xor-swizzled columns to dodge bank conflicts.
// ---------------------------------------------------------------------------
__global__ __launch_bounds__(256)
void vtrans_kernel(const bf16* __restrict__ xv, bf16* __restrict__ vtg) {
    __shared__ bf16 tile[64*72];
    int bh = blockIdx.x;
    int b = bh >> 5;
    int s0 = blockIdx.y * 64;
    int tid = threadIdx.x;
    // load 64 s-rows x 64 d, swizzle column-blocks by row
    for (int it = tid; it < 512; it += 256) {
        int row = it >> 3, blk = it & 7;
        short8 val = *(const short8*)(xv + (size_t)(b*S_ + s0 + row)*DIM_
                                      + (bh & 31)*64 + blk*8);
        *(short8*)(tile + row*72 + ((blk ^ (row & 7))*8)) = val;
    }
    __syncthreads();
    // write d-rows: thread (d = it>>3, s-block = it&7) gathers 8 s for fixed d
    for (int it = tid; it < 512; it += 256) {
        int d = it >> 3, sb = (it & 7)*8;
        short8 o;
        #pragma unroll
        for (int i = 0; i < 8; ++i) {
            int s = sb + i;
            o[i] = *(const short*)(tile + s*72 + (((d>>3) ^ (s & 7))*8) + (d & 7));
        }
        *(short8*)(vtg + ((size_t)bh*64 + d)*S_ + s0 + sb) = o;
    }
}

// ---------------------------------------------------------------------------
// MFMA flash attention + gate-combine epilogue.
// Block: (b,h,64-row Q-tile); 4 waves x 16 Q-rows. K-tiles of 64.
// XCD-grouped blockIdx; T14 reg-prefetch of next K/V tile; Ps XOR-swizzle;
// setprio around MFMA clusters.
// ---------------------------------------------------------------------------
__global__ __launch_bounds__(256)
void attn_mfma_kernel(const bf16* __restrict__ qr, const bf16* __restrict__ kr,
                      const bf16* __restrict__ vtg, const bf16* __restrict__ memcomb,
                      const void* __restrict__ gate, const int* __restrict__ flagp,
                      bf16* __restrict__ outc) {
    __shared__ bf16 Qs[64*72];
    __shared__ bf16 Ks[64*72];
    __shared__ bf16 Vt[64*72];   // [d][kk]
    __shared__ bf16 Ps[4][16*72];
    // XCD swizzle: group all 16 q-tiles of a (b,h) onto one XCD (assumes RR %8)
    int bid0 = blockIdx.x;
    int bid = ((bid0 & 7) << 8) | (bid0 >> 3);
    int qt = bid & 15;
    int h  = (bid >> 4) & 31;
    int b  = bid >> 9;
    int q0 = qt * 64;
    int tid = threadIdx.x;
    int w = tid >> 6, lane = tid & 63;
    int quad = lane >> 4, r16 = lane & 15;

    // stage Q tile + K/V tile 0
    for (int it = tid; it < 512; it += 256) {
        int row = it >> 3, c8 = (it & 7)*8;
        *(short8*)(Qs + row*72 + c8) =
            *(const short8*)(qr + (size_t)(b*S_ + q0 + row)*DIM_ + h*64 + c8);
        *(short8*)(Ks + row*72 + c8) =
            *(const short8*)(kr + (size_t)(b*S_ + row)*DIM_ + h*64 + c8);
        *(short8*)(Vt + row*72 + c8) =
            *(const short8*)(vtg + ((size_t)(b*H_ + h)*64 + row)*S_ + c8);
    }
    __syncthreads();
    short8 qf[2];
    #pragma unroll
    for (int kb = 0; kb < 2; ++kb)
        qf[kb] = *(const short8*)(Qs + (w*16 + r16)*72 + kb*32 + quad*8);

    float mrow[4] = {-1e30f,-1e30f,-1e30f,-1e30f};
    float lrow[4] = {0.f,0.f,0.f,0.f};
    floatx4 Ox[4];
    #pragma unroll
    for (int db = 0; db < 4; ++db) Ox[db] = (floatx4){0.f,0.f,0.f,0.f};

    // prefetch addressing (two 16B chunks per thread per array)
    int prow0 = tid >> 3, pc8 = (tid & 7)*8;   // rows 0..31
    int prow1 = prow0 + 32;                     // rows 32..63

    int ntiles = qt + 1;
    for (int kt = 0; kt < ntiles; ++kt) {
        int k0 = kt * 64;
        // T14: issue next tile's global loads into regs (latency hides under compute)
        short8 kn0, kn1, vn0, vn1;
        bool pre = (kt + 1 < ntiles);
        if (pre) {
            int k0n = k0 + 64;
            kn0 = *(const short8*)(kr + (size_t)(b*S_ + k0n + prow0)*DIM_ + h*64 + pc8);
            kn1 = *(const short8*)(kr + (size_t)(b*S_ + k0n + prow1)*DIM_ + h*64 + pc8);
            vn0 = *(const short8*)(vtg + ((size_t)(b*H_ + h)*64 + prow0)*S_ + k0n + pc8);
            vn1 = *(const short8*)(vtg + ((size_t)(b*H_ + h)*64 + prow1)*S_ + k0n + pc8);
        }

        // S strip: 16 q-rows x 64 k-cols per wave
        floatx4 Sbv[4];
        __builtin_amdgcn_s_setprio(1);
        #pragma unroll
        for (int nb = 0; nb < 4; ++nb) {
            floatx4 a = (floatx4){0.f,0.f,0.f,0.f};
            #pragma unroll
            for (int kb = 0; kb < 2; ++kb) {
                short8 kf = *(const short8*)(Ks + (nb*16 + r16)*72 + kb*32 + quad*8);
                a = __builtin_amdgcn_mfma_f32_16x16x32_bf16(qf[kb], kf, a, 0, 0, 0);
            }
            Sbv[nb] = a;
        }
        __builtin_amdgcn_s_setprio(0);
        // scale + causal mask
        float S4[4][4];
        #pragma unroll
        for (int nb = 0; nb < 4; ++nb)
            #pragma unroll
            for (int reg = 0; reg < 4; ++reg) {
                int qg = q0 + w*16 + quad*4 + reg;
                int kg = k0 + nb*16 + r16;
                float s = Sbv[nb][reg] * 0.125f;
                S4[nb][reg] = (kg > qg) ? -1e30f : s;
            }
        // online softmax (rows live across the 16 lanes of a quad)
        float alpha[4];
        #pragma unroll
        for (int reg = 0; reg < 4; ++reg) {
            float mx = fmaxf(fmaxf(S4[0][reg], S4[1][reg]),
                             fmaxf(S4[2][reg], S4[3][reg]));
            mx = fmaxf(mx, __shfl_xor(mx, 1, 64));
            mx = fmaxf(mx, __shfl_xor(mx, 2, 64));
            mx = fmaxf(mx, __shfl_xor(mx, 4, 64));
            mx = fmaxf(mx, __shfl_xor(mx, 8, 64));
            float mn = fmaxf(mrow[reg], mx);
            alpha[reg] = __expf(mrow[reg] - mn);
            mrow[reg] = mn;
            float rs = 0.f;
            #pragma unroll
            for (int nb = 0; nb < 4; ++nb) {
                float p = __expf(S4[nb][reg] - mn);
                S4[nb][reg] = p;
                rs += p;
            }
            rs += __shfl_xor(rs, 1, 64);
            rs += __shfl_xor(rs, 2, 64);
            rs += __shfl_xor(rs, 4, 64);
            rs += __shfl_xor(rs, 8, 64);
            lrow[reg] = lrow[reg]*alpha[reg] + rs;
        }
        // P -> LDS (C-layout write), XOR-swizzled cols for rows>=8 (bank-split)
        #pragma unroll
        for (int nb = 0; nb < 4; ++nb)
            #pragma unroll
            for (int reg = 0; reg < 4; ++reg)
                Ps[w][(quad*4 + reg)*72 + ((nb*16 + r16) ^ ((quad & 2) * 8))] =
                    __float2bfloat16(S4[nb][reg]);
        short8 pf[2];
        #pragma unroll
        for (int kb = 0; kb < 2; ++kb)
            pf[kb] = *(const short8*)(&Ps[w][0] + r16*72 +
                                      ((kb*32 + quad*8) ^ ((r16 & 8) << 1)));
        // O = O*alpha + P @ V
        #pragma unroll
        for (int db = 0; db < 4; ++db) {
            #pragma unroll
            for (int reg = 0; reg < 4; ++reg) Ox[db][reg] *= alpha[reg];
        }
        __builtin_amdgcn_s_setprio(1);
        #pragma unroll
        for (int db = 0; db < 4; ++db) {
            #pragma unroll
            for (int kb = 0; kb < 2; ++kb) {
                short8 vf = *(const short8*)(Vt + (db*16 + r16)*72 + kb*32 + quad*8);
                Ox[db] = __builtin_amdgcn_mfma_f32_16x16x32_bf16(pf[kb], vf, Ox[db], 0, 0, 0);
            }
        }
        __builtin_amdgcn_s_setprio(0);
        __syncthreads();   // all reads of Ks/Vt complete
        if (pre) {
            *(short8*)(Ks + prow0*72 + pc8) = kn0;
            *(short8*)(Ks + prow1*72 + pc8) = kn1;
            *(short8*)(Vt + prow0*72 + pc8) = vn0;
            *(short8*)(Vt + prow1*72 + pc8) = vn1;
        }
        __syncthreads();   // staged tile visible
    }

    int f = *flagp;
    float g = sigmoidf(dread(gate, h, f));
    #pragma unroll
    for (int db = 0; db < 4; ++db)
        #pragma unroll
        for (int reg = 0; reg < 4; ++reg) {
            int qg = q0 + w*16 + quad*4 + reg;
            int d  = db*16 + r16;
            float attn = Ox[db][reg] / lrow[reg];
            float comb = b2f(memcomb[((size_t)(b*H_ + h)*S_ + qg)*64 + d]);
            outc[(size_t)(b*S_ + qg)*DIM_ + h*64 + d] =
                __float2bfloat16(g*comb + (1.f - g)*attn);
        }
}

// ---------------------------------------------------------------------------
extern "C" void kernel_launch(void* const* d_in, const int* in_sizes, int n_in,
                              void* d_out, int out_size, void* d_ws, size_t ws_size,
                              hipStream_t stream) {
    const void* x        = d_in[0];
    const void* pq       = d_in[1];
    const void* cache_k  = d_in[2];
    const void* cache_v  = d_in[3];
    const void* mem_long = d_in[4];
    const void* mem_qry  = d_in[5];
    const void* norm_t   = d_in[6];
    const void* fcos     = d_in[7];
    const void* fsin     = d_in[8];
    // d_in[9] = mask (unused; causal applied analytically)
    const void* wq  = d_in[10];
    const void* wk  = d_in[11];
    const void* wv  = d_in[12];
    const void* wo  = d_in[13];
    const void* lq1 = d_in[14];
    const void* lq2 = d_in[15];
    const void* lk1 = d_in[16];
    const void* lk2 = d_in[17];
    const void* lv1 = d_in[18];
    const void* lv2 = d_in[19];
    const void* lo1 = d_in[20];
    const void* lo2 = d_in[21];
    const void* gate = d_in[22];
    const void* gmw  = d_in[23];
    const void* gmb  = d_in[24];

    const size_t NBSD = (size_t)BS_ * DIM_;   // 8388608
    const size_t NW   = (size_t)DIM_ * DIM_;  // 4194304
    int*  flag = (int*)d_ws;
    bf16* xb   = (bf16*)((char*)d_ws + 16);   // converted x
    bf16* wbuf = xb + NBSD;                   // fused (W + L2*L1) bf16
    bf16* xq   = wbuf + NW;
    bf16* xk   = xq + NBSD;
    bf16* xv   = xk + NBSD;
    bf16* outc = xv + NBSD;
    bf16* vtg  = outc + NBSD;                 // V transposed: [b,h,d,s]
    float* qsig = (float*)(vtg + NBSD);       // (slot kept; qscore now fused)
    float* meml = qsig + (size_t)B_*H_*S_;
    float* memq = meml + (size_t)B_*H_*HD_*HD_;
    float* nrmt = memq + (size_t)B_*H_*HD_*HD_;
    bf16* memcomb = (bf16*)d_out;   // parked; final GEMM overwrites d_out

    // extra QKV weight buffers OVERLAID on vtg (dead until vtrans; 2*NW==NBSD)
    bf16* wbK = (bf16*)vtg;
    bf16* wbV = wbK + NW;

    // partial buffers OVERLAID on dead regions (timeline-checked):
    // pbufL -> xb region   (xb dead after QKV GEMM)
    // pbufQ -> outc region (outc first written at attn, after memreduce)
    // pbufN -> wbuf region (wbuf dead between QKV GEMM and final wprep)
    float* pbufL = (float*)xb;
    float* pbufQ = (float*)outc;
    float* pbufN = (float*)wbuf;

    dim3 ggrid(DIM_/128, BS_/128);      // (16, 32) final GEMM
    dim3 ggrid3(3*DIM_/128, BS_/128);   // (48, 32) fused QKV GEMM
    dim3 wgrid(DIM_/256, DIM_);         // (8, 2048)
    dim3 wgrid3(DIM_/256, DIM_, 3);     // (8, 2048, 3)

    // 0. dtype detect
    detect_kernel<<<1, 256, 0, stream>>>(x, flag);
    // 1. convert x to bf16 (x8 vectorized)
    convert_kernel<<<(int)(NBSD/2048), 256, 0, stream>>>(x, xb, (int)NBSD, flag);
    // 2. projections: fold low-rank into weights (one launch), fused QKV GEMM
    wprep3_kernel<<<wgrid3, 256, 0, stream>>>(wq, wk, wv, lq1, lk1, lv1,
                                              lq2, lk2, lv2, flag,
                                              wbuf, wbK, wbV);
    gemm_mfma3_kernel<<<ggrid3, 256, 0, stream>>>(xb, wbuf, wbK, wbV, xq, xk, xv);
    // 3. V transpose for MFMA attention (overwrites wbK/wbV region)
    vtrans_kernel<<<dim3(B_*H_, S_/64), 256, 0, stream>>>(xv, vtg);
    // 4+5. memory accumulation (qscore fused): S-split partials + reduce
    mem_kernel<<<dim3(B_*H_, 8), 256, 0, stream>>>(cache_k, cache_v, pq, flag,
                                                   pbufL, pbufQ, pbufN);
    memreduce_kernel<<<(B_*H_*HD_*HD_)/256, 256, 0, stream>>>(
        pbufL, pbufQ, pbufN, mem_long, mem_qry, norm_t, flag, meml, memq, nrmt);
    // 6. memory readout + gate (consumes UN-roped xq); S-split grid
    memout_kernel<<<dim3(B_*H_, S_/64), 256, 0, stream>>>(xq, meml, memq, nrmt,
                                                          gmw, gmb, flag, memcomb);
    // 7. RoPE in place (xq + xk in one launch)
    rope_kernel<<<dim3((BS_*1024)/(256*4), 2), 256, 0, stream>>>(xq, xk, fcos, fsin, flag);
    // 8. MFMA causal attention + combine epilogue
    attn_mfma_kernel<<<B_*H_*(S_/64), 256, 0, stream>>>(xq, xk, vtg, memcomb,
                                                        gate, flag, outc);
    // 9. output projection
    wprep_kernel<<<wgrid, 256, 0, stream>>>(wo, lo1, lo2, flag, wbuf);
    gemm_mfma_kernel<0><<<ggrid, 256, 0, stream>>>(outc, wbuf, flag, d_out);
}